// Round 5
// baseline (155.987 us; speedup 1.0000x reference)
//
#include <hip/hip_runtime.h>
#include <hip/hip_bf16.h>

typedef __bf16 bf16x8 __attribute__((ext_vector_type(8)));
typedef float f32x4 __attribute__((ext_vector_type(4)));

#define NUM_TEAMS 100000
#define NUM_MATCHES 1000000
#define LOG2E 1.4426950408889634f
#define NWG 3125            // one block per 32-team tile, BOTH hcol-halves (100000 = 32*3125)
#define XQ 390              // NWG/8
#define XR 5                // NWG%8

__device__ __forceinline__ unsigned short f2bf(float x) {
    __hip_bfloat16 h = __float2bfloat16(x);
    return reinterpret_cast<unsigned short&>(h);
}
// single-instruction packed f32x2 -> bf16x2. No builtin on gfx950 (m240) -> asm.
__device__ __forceinline__ unsigned int cvtpk(float a, float b) {
    unsigned int r;
    asm("v_cvt_pk_bf16_f32 %0, %1, %2" : "=v"(r) : "v"(a), "v"(b));
    return r;
}
__device__ __forceinline__ float exp2_(float x) {
    float r; asm("v_exp_f32 %0, %1" : "=v"(r) : "v"(x)); return r;
}
__device__ __forceinline__ float rcp_(float x) {
    float r; asm("v_rcp_f32 %0, %1" : "=v"(r) : "v"(x)); return r;
}

// ---------------- prep: pack W fragment-major bf16; biases pre-scaled by log2e ----------------
// Wpk u16 index = G*16384 + gate*4096 + ks*512 + l4*128 + l15*8 + e
//   holds W[row = gate*128 + G*16 + l15][k = ks*32 + l4*8 + e]  (W = [W_ih | W_hh])
__global__ __launch_bounds__(256) void prep_kernel(
    const float* __restrict__ W_ih, const float* __restrict__ W_hh,
    const float* __restrict__ b_ih, const float* __restrict__ b_hh,
    unsigned short* __restrict__ Wpk, float* __restrict__ biasc)
{
    int gid = blockIdx.x * 256 + threadIdx.x;   // 131072 bf16 elements
    int e = gid & 7;
    int chunk = gid >> 3;                        // 16B chunk id
    int l15 = chunk & 15;
    int l4 = (chunk >> 4) & 3;
    int rest = chunk >> 6;
    int ks = rest & 7;
    int gate = (rest >> 3) & 3;
    int G = rest >> 5;
    int row = gate * 128 + G * 16 + l15;
    int k = ks * 32 + l4 * 8 + e;
    float v = (k < 128) ? W_ih[row * 128 + k] : W_hh[row * 128 + (k - 128)];
    Wpk[gid] = f2bf(v);
    if (gid < 512) {
        float b = b_ih[gid] + b_hh[gid];
        float scale = ((gid >> 7) == 2) ? (2.0f * LOG2E) : (-LOG2E);
        biasc[gid] = b * scale;
    }
}

// ---------------- LSTM + fused proj, both halves per block ----------------
// Tile: 32 teams x FULL 128 hcols, processed as two sequential 64-hcol halves.
// A ([inputs|hx], the dominant HBM stream) is staged ONCE per team (round 0
// staged it twice — every other round's FETCH/dur ratio pinned at ~1 TB/s says
// first-touch HBM bytes set the duration). h-halves go through an 8 KB LDS
// buffer; proj halves combine in registers -> projP holds FINAL values (match
// kernel traffic halves too). Work/block = round 0; barriers/work 6->4;
// LDS 27.6 KB -> 5 blocks/CU; acc 32 AGPR -> 5 waves/SIMD (launch_bounds(256,5)),
// i.e. 20 waves/CU in 5 independent blocks. cx register-prefetched a phase early
// (cx0 under stage+K0, cx1 under proj0+K1). 100000%32==0: no clamps anywhere.
__global__ __launch_bounds__(256, 5) void lstm_kernel(
    const float* __restrict__ inputs, const float* __restrict__ hx,
    const float* __restrict__ cx, const unsigned short* __restrict__ Wpk,
    const float* __restrict__ biasc, const float* __restrict__ W_out,
    float* __restrict__ projP)
{
    __shared__ __align__(16) unsigned short Abf[32 * 256];  // 16 KB bf16 A tile (persists)
    __shared__ __align__(16) float Hf[32 * 64];             // 8 KB h half-tile
    __shared__ float Wlds[768];
    const int tid = threadIdx.x;

    // bijective chunked XCD swizzle
    const int orig = blockIdx.x;
    const int xcd = orig & 7, idx = orig >> 3;
    const int tile = (xcd < XR ? xcd * (XQ + 1) : XR * (XQ + 1) + (xcd - XR) * XQ) + idx;
    const int brow = tile * 32;

    const int lane = tid & 63;
    const int w = tid >> 6;                          // wave 0..3
    const int l15 = lane & 15, l4 = lane >> 4;
    const int hl = w * 16 + l15;                     // hcol-local 0..63

    // ---- stage A = [inputs | hx] as bf16, XOR-swizzled; 8 contiguous float4/thread ----
    {
        const int r = tid >> 3, seg = tid & 7;       // row 0..31, 128B col-chunk 0..7
        const float* src = ((seg < 4) ? inputs + seg * 32 : hx + (seg - 4) * 32)
                           + (size_t)(brow + r) * 128;
        float4 v0 = *reinterpret_cast<const float4*>(src);
        float4 v1 = *reinterpret_cast<const float4*>(src + 4);
        float4 v2 = *reinterpret_cast<const float4*>(src + 8);
        float4 v3 = *reinterpret_cast<const float4*>(src + 12);
        float4 v4 = *reinterpret_cast<const float4*>(src + 16);
        float4 v5 = *reinterpret_cast<const float4*>(src + 20);
        float4 v6 = *reinterpret_cast<const float4*>(src + 24);
        float4 v7 = *reinterpret_cast<const float4*>(src + 28);
        char* lbw = reinterpret_cast<char*>(Abf);
        const int base = r * 512 + seg * 64;
        const int swz = (r & 7) << 4;
        uint4 q0, q1;
        q0.x = cvtpk(v0.x, v0.y); q0.y = cvtpk(v0.z, v0.w);
        q0.z = cvtpk(v1.x, v1.y); q0.w = cvtpk(v1.z, v1.w);
        q1.x = cvtpk(v2.x, v2.y); q1.y = cvtpk(v2.z, v2.w);
        q1.z = cvtpk(v3.x, v3.y); q1.w = cvtpk(v3.z, v3.w);
        *reinterpret_cast<uint4*>(lbw + (base ^ swz)) = q0;
        *reinterpret_cast<uint4*>(lbw + ((base + 16) ^ swz)) = q1;
        q0.x = cvtpk(v4.x, v4.y); q0.y = cvtpk(v4.z, v4.w);
        q0.z = cvtpk(v5.x, v5.y); q0.w = cvtpk(v5.z, v5.w);
        q1.x = cvtpk(v6.x, v6.y); q1.y = cvtpk(v6.z, v6.w);
        q1.z = cvtpk(v7.x, v7.y); q1.w = cvtpk(v7.z, v7.w);
        *reinterpret_cast<uint4*>(lbw + ((base + 32) ^ swz)) = q0;
        *reinterpret_cast<uint4*>(lbw + ((base + 48) ^ swz)) = q1;
        Wlds[tid] = W_out[tid];
        Wlds[256 + tid] = W_out[256 + tid];
        Wlds[512 + tid] = W_out[512 + tid];
    }

    // cx for half 0 — issued now, consumed after K0 (latency hides under stage+K0)
    float cxa[8];
    #pragma unroll
    for (int m = 0; m < 2; ++m)
        #pragma unroll
        for (int j = 0; j < 4; ++j)
            cxa[m * 4 + j] = cx[(size_t)(brow + m * 16 + l4 * 4 + j) * 128 + hl];

    const int swzA = (l15 & 7) << 4;
    const int kf = l4 * 16;
    const char* pArow = reinterpret_cast<const char*>(Abf) + l15 * 512;

    float p0, p1, p2, p3, p4, p5;                    // half-0 proj partials (live across half 1)

    __syncthreads();                                 // S0: Abf + Wlds ready

    #pragma unroll
    for (int ch = 0; ch < 2; ++ch) {
        const int hcol = ch * 64 + hl;
        const unsigned short* bpg = Wpk + (size_t)(ch * 4 + w) * 16384 + lane * 8;
        const float bic = biasc[hcol];
        const float bfc = biasc[128 + hcol];
        const float bgc = biasc[256 + hcol];
        const float boc = biasc[384 + hcol];

        // ---- K-loop: K = 256 in steps of 32; A from LDS, B from L2 ----
        f32x4 acc[2][4] = {};                        // [m][gate], 32 AGPRs
        #pragma unroll
        for (int ks = 0; ks < 8; ++ks) {
            bf16x8 b0 = *(const bf16x8*)(bpg + ks * 512);
            bf16x8 b1 = *(const bf16x8*)(bpg + 4096 + ks * 512);
            bf16x8 b2 = *(const bf16x8*)(bpg + 8192 + ks * 512);
            bf16x8 b3 = *(const bf16x8*)(bpg + 12288 + ks * 512);
            const int ko = (ks * 64 + kf) ^ swzA;
            #pragma unroll
            for (int m = 0; m < 2; ++m) {
                bf16x8 af = *(const bf16x8*)(pArow + m * 8192 + ko);
                acc[m][0] = __builtin_amdgcn_mfma_f32_16x16x32_bf16(af, b0, acc[m][0], 0, 0, 0);
                acc[m][1] = __builtin_amdgcn_mfma_f32_16x16x32_bf16(af, b1, acc[m][1], 0, 0, 0);
                acc[m][2] = __builtin_amdgcn_mfma_f32_16x16x32_bf16(af, b2, acc[m][2], 0, 0, 0);
                acc[m][3] = __builtin_amdgcn_mfma_f32_16x16x32_bf16(af, b3, acc[m][3], 0, 0, 0);
            }
        }

        // ---- activations; h -> swizzled f32 [32][64] in Hf ----
        // C/D layout: col = l15 -> hcol, row = l4*4 + j -> team-local
        {
            char* lb = reinterpret_cast<char*>(Hf);
            #pragma unroll
            for (int m = 0; m < 2; ++m) {
                #pragma unroll
                for (int j = 0; j < 4; ++j) {
                    float si = rcp_(1.0f + exp2_(fmaf(acc[m][0][j], -LOG2E, bic)));
                    float sf = rcp_(1.0f + exp2_(fmaf(acc[m][1][j], -LOG2E, bfc)));
                    float tg = fmaf(-2.0f, rcp_(1.0f + exp2_(fmaf(acc[m][2][j], 2.0f * LOG2E, bgc))), 1.0f);
                    float so = rcp_(1.0f + exp2_(fmaf(acc[m][3][j], -LOG2E, boc)));
                    float cn = fmaf(sf, cxa[m * 4 + j], si * tg);
                    float tc = fmaf(-2.0f, rcp_(1.0f + exp2_(cn * (2.0f * LOG2E))), 1.0f);
                    float hn = so * tc;
                    int t = m * 16 + l4 * 4 + j;
                    *reinterpret_cast<float*>(lb + ((t * 256 + hl * 4) ^ ((t & 7) << 4))) = hn;
                }
            }
        }

        // prefetch cx for half 1 (consumed next act; hides under proj0 + K1)
        if (ch == 0) {
            #pragma unroll
            for (int m = 0; m < 2; ++m)
                #pragma unroll
                for (int j = 0; j < 4; ++j)
                    cxa[m * 4 + j] = cx[(size_t)(brow + m * 16 + l4 * 4 + j) * 128 + 64 + hl];
        }

        __syncthreads();                             // Hf(ch) visible to all

        // ---- proj: 8 threads/team, 8 hcols each, 6 outputs; halves combine in regs ----
        {
            int tl = tid >> 3, sub = tid & 7;        // team-local 0..31, sub 0..7
            const char* lb = reinterpret_cast<const char*>(Hf);
            int hbase = tl * 256 + sub * 32;
            int hswz = (tl & 7) << 4;
            float a0 = 0.f, a1 = 0.f, a2 = 0.f, a3 = 0.f, a4 = 0.f, a5 = 0.f;
            #pragma unroll
            for (int c = 0; c < 2; ++c) {
                f32x4 h4 = *reinterpret_cast<const f32x4*>(lb + ((hbase + c * 16) ^ hswz));
                #pragma unroll
                for (int i = 0; i < 4; ++i) {
                    float h = h4[i];
                    int col = ch * 64 + sub * 8 + c * 4 + i;     // global hcol 0..127
                    a0 += h * Wlds[col];       a1 += h * Wlds[256 + col]; a2 += h * Wlds[512 + col];
                    a3 += h * Wlds[128 + col]; a4 += h * Wlds[384 + col]; a5 += h * Wlds[640 + col];
                }
            }
            a0 += __shfl_xor(a0, 1); a1 += __shfl_xor(a1, 1); a2 += __shfl_xor(a2, 1);
            a3 += __shfl_xor(a3, 1); a4 += __shfl_xor(a4, 1); a5 += __shfl_xor(a5, 1);
            a0 += __shfl_xor(a0, 2); a1 += __shfl_xor(a1, 2); a2 += __shfl_xor(a2, 2);
            a3 += __shfl_xor(a3, 2); a4 += __shfl_xor(a4, 2); a5 += __shfl_xor(a5, 2);
            a0 += __shfl_xor(a0, 4); a1 += __shfl_xor(a1, 4); a2 += __shfl_xor(a2, 4);
            a3 += __shfl_xor(a3, 4); a4 += __shfl_xor(a4, 4); a5 += __shfl_xor(a5, 4);
            if (ch == 0) {
                p0 = a0; p1 = a1; p2 = a2; p3 = a3; p4 = a4; p5 = a5;
            } else if (sub == 0) {
                float4* o = reinterpret_cast<float4*>(projP + (size_t)(brow + tl) * 8);
                o[0] = make_float4(p0 + a0, p1 + a1, p2 + a2, p2 + a2);  // home final
                o[1] = make_float4(p3 + a3, p4 + a4, p5 + a5, p5 + a5);  // away final
            }
        }
        if (ch == 0) __syncthreads();                // proj0 reads done before act1 rewrites Hf
    }
}

// ---------------- match head: gather finals; logits + b_out ; softmax ----------------
__global__ __launch_bounds__(256) void match_kernel(
    const int* __restrict__ matches, const float* __restrict__ projP,
    const float* __restrict__ b_out, float* __restrict__ out)
{
    int m = blockIdx.x * 256 + threadIdx.x;
    if (m >= NUM_MATCHES) return;
    int2 mi = reinterpret_cast<const int2*>(matches)[m];
    const float4* pp = reinterpret_cast<const float4*>(projP);
    float4 hv = pp[(size_t)mi.x * 2 + 0];            // home
    float4 av = pp[(size_t)mi.y * 2 + 1];            // away
    float l0 = hv.x + av.x + b_out[0];
    float l1 = hv.y + av.y + b_out[1];
    float l2 = hv.z + av.z + b_out[2];
    float mx = fmaxf(l0, fmaxf(l1, l2));
    float e0 = __expf(l0 - mx), e1 = __expf(l1 - mx), e2 = __expf(l2 - mx);
    float inv = 1.0f / (e0 + e1 + e2);
    out[3 * m + 0] = e0 * inv;
    out[3 * m + 1] = e1 * inv;
    out[3 * m + 2] = e2 * inv;
}

extern "C" void kernel_launch(void* const* d_in, const int* in_sizes, int n_in,
                              void* d_out, int out_size, void* d_ws, size_t ws_size,
                              hipStream_t stream) {
    const float* inputs = (const float*)d_in[0];
    const float* hx     = (const float*)d_in[1];
    const float* cx     = (const float*)d_in[2];
    const int*   matches= (const int*)d_in[3];
    const float* W_ih   = (const float*)d_in[4];
    const float* W_hh   = (const float*)d_in[5];
    const float* b_ih   = (const float*)d_in[6];
    const float* b_hh   = (const float*)d_in[7];
    const float* W_out  = (const float*)d_in[8];
    const float* b_out  = (const float*)d_in[9];
    float* out = (float*)d_out;

    char* ws = (char*)d_ws;
    unsigned short* Wpk  = (unsigned short*)ws;                  // 256 KB fragment-major
    float* biasc         = (float*)(ws + 262144);                // 2 KB
    float* projP         = (float*)(ws + (1 << 20));             // 100000*8*4 = 3.2 MB (final)

    prep_kernel <<<512, 256, 0, stream>>>(W_ih, W_hh, b_ih, b_hh, Wpk, biasc);
    lstm_kernel <<<NWG, 256, 0, stream>>>(inputs, hx, cx, Wpk, biasc, W_out, projP);
    match_kernel<<<(NUM_MATCHES + 255) / 256, 256, 0, stream>>>(matches, projP, b_out, out);
}

// Round 6
// 78.409 us; speedup vs baseline: 1.9894x; 1.9894x over previous
//
#include <hip/hip_runtime.h>
#include <hip/hip_bf16.h>

typedef __bf16 bf16x8 __attribute__((ext_vector_type(8)));
typedef float f32x4 __attribute__((ext_vector_type(4)));

#define NUM_TEAMS 100000
#define NUM_MATCHES 1000000
#define LOG2E 1.4426950408889634f
#define NWG 3125            // one block per 32-team tile, BOTH hcol-halves (100000 = 32*3125)
#define XQ 390              // NWG/8
#define XR 5                // NWG%8

__device__ __forceinline__ unsigned short f2bf(float x) {
    __hip_bfloat16 h = __float2bfloat16(x);
    return reinterpret_cast<unsigned short&>(h);
}
// single-instruction packed f32x2 -> bf16x2. No builtin on gfx950 (m240) -> asm.
__device__ __forceinline__ unsigned int cvtpk(float a, float b) {
    unsigned int r;
    asm("v_cvt_pk_bf16_f32 %0, %1, %2" : "=v"(r) : "v"(a), "v"(b));
    return r;
}
__device__ __forceinline__ float exp2_(float x) {
    float r; asm("v_exp_f32 %0, %1" : "=v"(r) : "v"(x)); return r;
}
__device__ __forceinline__ float rcp_(float x) {
    float r; asm("v_rcp_f32 %0, %1" : "=v"(r) : "v"(x)); return r;
}

// ---------------- prep: pack W fragment-major bf16; biases pre-scaled by log2e ----------------
// Wpk u16 index = G*16384 + gate*4096 + ks*512 + l4*128 + l15*8 + e
//   holds W[row = gate*128 + G*16 + l15][k = ks*32 + l4*8 + e]  (W = [W_ih | W_hh])
__global__ __launch_bounds__(256) void prep_kernel(
    const float* __restrict__ W_ih, const float* __restrict__ W_hh,
    const float* __restrict__ b_ih, const float* __restrict__ b_hh,
    unsigned short* __restrict__ Wpk, float* __restrict__ biasc)
{
    int gid = blockIdx.x * 256 + threadIdx.x;   // 131072 bf16 elements
    int e = gid & 7;
    int chunk = gid >> 3;                        // 16B chunk id
    int l15 = chunk & 15;
    int l4 = (chunk >> 4) & 3;
    int rest = chunk >> 6;
    int ks = rest & 7;
    int gate = (rest >> 3) & 3;
    int G = rest >> 5;
    int row = gate * 128 + G * 16 + l15;
    int k = ks * 32 + l4 * 8 + e;
    float v = (k < 128) ? W_ih[row * 128 + k] : W_hh[row * 128 + (k - 128)];
    Wpk[gid] = f2bf(v);
    if (gid < 512) {
        float b = b_ih[gid] + b_hh[gid];
        float scale = ((gid >> 7) == 2) ? (2.0f * LOG2E) : (-LOG2E);
        biasc[gid] = b * scale;
    }
}

// ---------------- LSTM + fused proj, both halves per block ----------------
// Round-5 structure (A staged ONCE per team; projP final) with the spill removed:
// __launch_bounds__(256,4) -> 128 regs/wave = 32 acc AGPR + <=96 arch. Peak live
// set ~70 -> no spill (r5's (256,5)=102 budget spilled: WRITE_SIZE 6->223 MB).
// LDS 27.6 KB (A 16 + Hf 8 + W 3) -> regs cap 4 blocks/CU x 4 waves = 16 waves/CU,
// identical occupancy to round 0; the deltas vs r0 are A first-touch halved,
// match-kernel reads halved, 8-deep staging, 4 barriers per 2 half-tiles.
// Half-1 K-loop placed BEFORE proj0 (independent) so proj0's LDS reads overlap
// other waves' MFMA instead of sitting between two barriers.
__global__ __launch_bounds__(256, 4) void lstm_kernel(
    const float* __restrict__ inputs, const float* __restrict__ hx,
    const float* __restrict__ cx, const unsigned short* __restrict__ Wpk,
    const float* __restrict__ biasc, const float* __restrict__ W_out,
    float* __restrict__ projP)
{
    __shared__ __align__(16) unsigned short Abf[32 * 256];  // 16 KB bf16 A tile (persists)
    __shared__ __align__(16) float Hf[32 * 64];             // 8 KB h half-tile
    __shared__ float Wlds[768];
    const int tid = threadIdx.x;

    // bijective chunked XCD swizzle
    const int orig = blockIdx.x;
    const int xcd = orig & 7, idx = orig >> 3;
    const int tile = (xcd < XR ? xcd * (XQ + 1) : XR * (XQ + 1) + (xcd - XR) * XQ) + idx;
    const int brow = tile * 32;

    const int lane = tid & 63;
    const int w = tid >> 6;                          // wave 0..3
    const int l15 = lane & 15, l4 = lane >> 4;
    const int hl = w * 16 + l15;                     // hcol-local 0..63

    // ---- stage A = [inputs | hx] as bf16, XOR-swizzled; 8 float4/thread in flight ----
    {
        const int r = tid >> 3, seg = tid & 7;       // row 0..31, 128B col-chunk 0..7
        const float* src = ((seg < 4) ? inputs + seg * 32 : hx + (seg - 4) * 32)
                           + (size_t)(brow + r) * 128;
        float4 v0 = *reinterpret_cast<const float4*>(src);
        float4 v1 = *reinterpret_cast<const float4*>(src + 4);
        float4 v2 = *reinterpret_cast<const float4*>(src + 8);
        float4 v3 = *reinterpret_cast<const float4*>(src + 12);
        float4 v4 = *reinterpret_cast<const float4*>(src + 16);
        float4 v5 = *reinterpret_cast<const float4*>(src + 20);
        float4 v6 = *reinterpret_cast<const float4*>(src + 24);
        float4 v7 = *reinterpret_cast<const float4*>(src + 28);
        char* lbw = reinterpret_cast<char*>(Abf);
        const int base = r * 512 + seg * 64;
        const int swz = (r & 7) << 4;
        uint4 q0, q1;
        q0.x = cvtpk(v0.x, v0.y); q0.y = cvtpk(v0.z, v0.w);
        q0.z = cvtpk(v1.x, v1.y); q0.w = cvtpk(v1.z, v1.w);
        q1.x = cvtpk(v2.x, v2.y); q1.y = cvtpk(v2.z, v2.w);
        q1.z = cvtpk(v3.x, v3.y); q1.w = cvtpk(v3.z, v3.w);
        *reinterpret_cast<uint4*>(lbw + (base ^ swz)) = q0;
        *reinterpret_cast<uint4*>(lbw + ((base + 16) ^ swz)) = q1;
        q0.x = cvtpk(v4.x, v4.y); q0.y = cvtpk(v4.z, v4.w);
        q0.z = cvtpk(v5.x, v5.y); q0.w = cvtpk(v5.z, v5.w);
        q1.x = cvtpk(v6.x, v6.y); q1.y = cvtpk(v6.z, v6.w);
        q1.z = cvtpk(v7.x, v7.y); q1.w = cvtpk(v7.z, v7.w);
        *reinterpret_cast<uint4*>(lbw + ((base + 32) ^ swz)) = q0;
        *reinterpret_cast<uint4*>(lbw + ((base + 48) ^ swz)) = q1;
        Wlds[tid] = W_out[tid];
        Wlds[256 + tid] = W_out[256 + tid];
        Wlds[512 + tid] = W_out[512 + tid];
    }

    // cx for half 0 — issued now, consumed after K0 (latency hides under stage+K0)
    float cxa[8];
    #pragma unroll
    for (int m = 0; m < 2; ++m)
        #pragma unroll
        for (int j = 0; j < 4; ++j)
            cxa[m * 4 + j] = cx[(size_t)(brow + m * 16 + l4 * 4 + j) * 128 + hl];

    const int swzA = (l15 & 7) << 4;
    const int kf = l4 * 16;
    const char* pArow = reinterpret_cast<const char*>(Abf) + l15 * 512;
    const int tl = tid >> 3, sub = tid & 7;          // proj: team-local 0..31, sub 0..7
    const int hbase = tl * 256 + sub * 32;
    const int hswz = (tl & 7) << 4;

    __syncthreads();                                 // S0: Abf + Wlds ready

    // ================= half 0 =================
    f32x4 acc[2][4] = {};                            // [m][gate], 32 AGPRs
    {
        const unsigned short* bpg = Wpk + (size_t)w * 16384 + lane * 8;
        #pragma unroll
        for (int ks = 0; ks < 8; ++ks) {
            bf16x8 b0 = *(const bf16x8*)(bpg + ks * 512);
            bf16x8 b1 = *(const bf16x8*)(bpg + 4096 + ks * 512);
            bf16x8 b2 = *(const bf16x8*)(bpg + 8192 + ks * 512);
            bf16x8 b3 = *(const bf16x8*)(bpg + 12288 + ks * 512);
            const int ko = (ks * 64 + kf) ^ swzA;
            #pragma unroll
            for (int m = 0; m < 2; ++m) {
                bf16x8 af = *(const bf16x8*)(pArow + m * 8192 + ko);
                acc[m][0] = __builtin_amdgcn_mfma_f32_16x16x32_bf16(af, b0, acc[m][0], 0, 0, 0);
                acc[m][1] = __builtin_amdgcn_mfma_f32_16x16x32_bf16(af, b1, acc[m][1], 0, 0, 0);
                acc[m][2] = __builtin_amdgcn_mfma_f32_16x16x32_bf16(af, b2, acc[m][2], 0, 0, 0);
                acc[m][3] = __builtin_amdgcn_mfma_f32_16x16x32_bf16(af, b3, acc[m][3], 0, 0, 0);
            }
        }
    }
    // act0: h -> swizzled f32 [32][64] in Hf   (C/D: col=l15->hcol, row=l4*4+j)
    {
        const float bic = biasc[hl];
        const float bfc = biasc[128 + hl];
        const float bgc = biasc[256 + hl];
        const float boc = biasc[384 + hl];
        char* lb = reinterpret_cast<char*>(Hf);
        #pragma unroll
        for (int m = 0; m < 2; ++m)
            #pragma unroll
            for (int j = 0; j < 4; ++j) {
                float si = rcp_(1.0f + exp2_(fmaf(acc[m][0][j], -LOG2E, bic)));
                float sf = rcp_(1.0f + exp2_(fmaf(acc[m][1][j], -LOG2E, bfc)));
                float tg = fmaf(-2.0f, rcp_(1.0f + exp2_(fmaf(acc[m][2][j], 2.0f * LOG2E, bgc))), 1.0f);
                float so = rcp_(1.0f + exp2_(fmaf(acc[m][3][j], -LOG2E, boc)));
                float cn = fmaf(sf, cxa[m * 4 + j], si * tg);
                float tc = fmaf(-2.0f, rcp_(1.0f + exp2_(cn * (2.0f * LOG2E))), 1.0f);
                float hn = so * tc;
                int t = m * 16 + l4 * 4 + j;
                *reinterpret_cast<float*>(lb + ((t * 256 + hl * 4) ^ ((t & 7) << 4))) = hn;
            }
    }
    // prefetch cx for half 1 (consumed in act1; hides under K1 + proj0)
    #pragma unroll
    for (int m = 0; m < 2; ++m)
        #pragma unroll
        for (int j = 0; j < 4; ++j)
            cxa[m * 4 + j] = cx[(size_t)(brow + m * 16 + l4 * 4 + j) * 128 + 64 + hl];

    __syncthreads();                                 // S1: Hf(0) visible

    // ================= half 1 K-loop first (independent of proj0 -> overlap) =================
    f32x4 acc1[2][4] = {};
    {
        const unsigned short* bpg = Wpk + (size_t)(4 + w) * 16384 + lane * 8;
        #pragma unroll
        for (int ks = 0; ks < 8; ++ks) {
            bf16x8 b0 = *(const bf16x8*)(bpg + ks * 512);
            bf16x8 b1 = *(const bf16x8*)(bpg + 4096 + ks * 512);
            bf16x8 b2 = *(const bf16x8*)(bpg + 8192 + ks * 512);
            bf16x8 b3 = *(const bf16x8*)(bpg + 12288 + ks * 512);
            const int ko = (ks * 64 + kf) ^ swzA;
            #pragma unroll
            for (int m = 0; m < 2; ++m) {
                bf16x8 af = *(const bf16x8*)(pArow + m * 8192 + ko);
                acc1[m][0] = __builtin_amdgcn_mfma_f32_16x16x32_bf16(af, b0, acc1[m][0], 0, 0, 0);
                acc1[m][1] = __builtin_amdgcn_mfma_f32_16x16x32_bf16(af, b1, acc1[m][1], 0, 0, 0);
                acc1[m][2] = __builtin_amdgcn_mfma_f32_16x16x32_bf16(af, b2, acc1[m][2], 0, 0, 0);
                acc1[m][3] = __builtin_amdgcn_mfma_f32_16x16x32_bf16(af, b3, acc1[m][3], 0, 0, 0);
            }
        }
    }
    // proj0: 8 threads/team, 8 hcols each -> p0..p5 partials
    float p0 = 0.f, p1 = 0.f, p2 = 0.f, p3 = 0.f, p4 = 0.f, p5 = 0.f;
    {
        const char* lb = reinterpret_cast<const char*>(Hf);
        #pragma unroll
        for (int c = 0; c < 2; ++c) {
            f32x4 h4 = *reinterpret_cast<const f32x4*>(lb + ((hbase + c * 16) ^ hswz));
            #pragma unroll
            for (int i = 0; i < 4; ++i) {
                float h = h4[i];
                int col = sub * 8 + c * 4 + i;               // global hcol 0..63
                p0 += h * Wlds[col];       p1 += h * Wlds[256 + col]; p2 += h * Wlds[512 + col];
                p3 += h * Wlds[128 + col]; p4 += h * Wlds[384 + col]; p5 += h * Wlds[640 + col];
            }
        }
    }
    __syncthreads();                                 // S2: proj0 reads done; acc1 ready

    // act1 -> Hf
    {
        const float bic = biasc[64 + hl];
        const float bfc = biasc[192 + hl];
        const float bgc = biasc[320 + hl];
        const float boc = biasc[448 + hl];
        char* lb = reinterpret_cast<char*>(Hf);
        #pragma unroll
        for (int m = 0; m < 2; ++m)
            #pragma unroll
            for (int j = 0; j < 4; ++j) {
                float si = rcp_(1.0f + exp2_(fmaf(acc1[m][0][j], -LOG2E, bic)));
                float sf = rcp_(1.0f + exp2_(fmaf(acc1[m][1][j], -LOG2E, bfc)));
                float tg = fmaf(-2.0f, rcp_(1.0f + exp2_(fmaf(acc1[m][2][j], 2.0f * LOG2E, bgc))), 1.0f);
                float so = rcp_(1.0f + exp2_(fmaf(acc1[m][3][j], -LOG2E, boc)));
                float cn = fmaf(sf, cxa[m * 4 + j], si * tg);
                float tc = fmaf(-2.0f, rcp_(1.0f + exp2_(cn * (2.0f * LOG2E))), 1.0f);
                float hn = so * tc;
                int t = m * 16 + l4 * 4 + j;
                *reinterpret_cast<float*>(lb + ((t * 256 + hl * 4) ^ ((t & 7) << 4))) = hn;
            }
    }
    __syncthreads();                                 // S3: Hf(1) visible

    // proj1 + combine + reduce + store finals
    {
        const char* lb = reinterpret_cast<const char*>(Hf);
        #pragma unroll
        for (int c = 0; c < 2; ++c) {
            f32x4 h4 = *reinterpret_cast<const f32x4*>(lb + ((hbase + c * 16) ^ hswz));
            #pragma unroll
            for (int i = 0; i < 4; ++i) {
                float h = h4[i];
                int col = 64 + sub * 8 + c * 4 + i;          // global hcol 64..127
                p0 += h * Wlds[col];       p1 += h * Wlds[256 + col]; p2 += h * Wlds[512 + col];
                p3 += h * Wlds[128 + col]; p4 += h * Wlds[384 + col]; p5 += h * Wlds[640 + col];
            }
        }
        p0 += __shfl_xor(p0, 1); p1 += __shfl_xor(p1, 1); p2 += __shfl_xor(p2, 1);
        p3 += __shfl_xor(p3, 1); p4 += __shfl_xor(p4, 1); p5 += __shfl_xor(p5, 1);
        p0 += __shfl_xor(p0, 2); p1 += __shfl_xor(p1, 2); p2 += __shfl_xor(p2, 2);
        p3 += __shfl_xor(p3, 2); p4 += __shfl_xor(p4, 2); p5 += __shfl_xor(p5, 2);
        p0 += __shfl_xor(p0, 4); p1 += __shfl_xor(p1, 4); p2 += __shfl_xor(p2, 4);
        p3 += __shfl_xor(p3, 4); p4 += __shfl_xor(p4, 4); p5 += __shfl_xor(p5, 4);
        if (sub == 0) {
            float4* o = reinterpret_cast<float4*>(projP + (size_t)(brow + tl) * 8);
            o[0] = make_float4(p0, p1, p2, p2);      // home final
            o[1] = make_float4(p3, p4, p5, p5);      // away final
        }
    }
}

// ---------------- match head: gather finals; logits + b_out ; softmax ----------------
__global__ __launch_bounds__(256) void match_kernel(
    const int* __restrict__ matches, const float* __restrict__ projP,
    const float* __restrict__ b_out, float* __restrict__ out)
{
    int m = blockIdx.x * 256 + threadIdx.x;
    if (m >= NUM_MATCHES) return;
    int2 mi = reinterpret_cast<const int2*>(matches)[m];
    const float4* pp = reinterpret_cast<const float4*>(projP);
    float4 hv = pp[(size_t)mi.x * 2 + 0];            // home
    float4 av = pp[(size_t)mi.y * 2 + 1];            // away
    float l0 = hv.x + av.x + b_out[0];
    float l1 = hv.y + av.y + b_out[1];
    float l2 = hv.z + av.z + b_out[2];
    float mx = fmaxf(l0, fmaxf(l1, l2));
    float e0 = __expf(l0 - mx), e1 = __expf(l1 - mx), e2 = __expf(l2 - mx);
    float inv = 1.0f / (e0 + e1 + e2);
    out[3 * m + 0] = e0 * inv;
    out[3 * m + 1] = e1 * inv;
    out[3 * m + 2] = e2 * inv;
}

extern "C" void kernel_launch(void* const* d_in, const int* in_sizes, int n_in,
                              void* d_out, int out_size, void* d_ws, size_t ws_size,
                              hipStream_t stream) {
    const float* inputs = (const float*)d_in[0];
    const float* hx     = (const float*)d_in[1];
    const float* cx     = (const float*)d_in[2];
    const int*   matches= (const int*)d_in[3];
    const float* W_ih   = (const float*)d_in[4];
    const float* W_hh   = (const float*)d_in[5];
    const float* b_ih   = (const float*)d_in[6];
    const float* b_hh   = (const float*)d_in[7];
    const float* W_out  = (const float*)d_in[8];
    const float* b_out  = (const float*)d_in[9];
    float* out = (float*)d_out;

    char* ws = (char*)d_ws;
    unsigned short* Wpk  = (unsigned short*)ws;                  // 256 KB fragment-major
    float* biasc         = (float*)(ws + 262144);                // 2 KB
    float* projP         = (float*)(ws + (1 << 20));             // 100000*8*4 = 3.2 MB (final)

    prep_kernel <<<512, 256, 0, stream>>>(W_ih, W_hh, b_ih, b_hh, Wpk, biasc);
    lstm_kernel <<<NWG, 256, 0, stream>>>(inputs, hx, cx, Wpk, biasc, W_out, projP);
    match_kernel<<<(NUM_MATCHES + 255) / 256, 256, 0, stream>>>(matches, projP, b_out, out);
}

// Round 7
// 74.793 us; speedup vs baseline: 2.0856x; 1.0483x over previous
//
#include <hip/hip_runtime.h>
#include <hip/hip_bf16.h>

typedef __bf16 bf16x8 __attribute__((ext_vector_type(8)));
typedef float f32x4 __attribute__((ext_vector_type(4)));

#define NUM_TEAMS 100000
#define NUM_MATCHES 1000000
#define LOG2E 1.4426950408889634f
#define NWG 3126            // 1563 team-tiles x 2 hcol-halves
#define XQ 390              // NWG/8
#define XR 6                // NWG%8

__device__ __forceinline__ unsigned short f2bf(float x) {
    __hip_bfloat16 h = __float2bfloat16(x);
    return reinterpret_cast<unsigned short&>(h);
}
// single-instruction packed f32x2 -> bf16x2. No builtin on gfx950 (m240) -> asm.
__device__ __forceinline__ unsigned int cvtpk(float a, float b) {
    unsigned int r;
    asm("v_cvt_pk_bf16_f32 %0, %1, %2" : "=v"(r) : "v"(a), "v"(b));
    return r;
}
__device__ __forceinline__ float exp2_(float x) {
    float r; asm("v_exp_f32 %0, %1" : "=v"(r) : "v"(x)); return r;
}
__device__ __forceinline__ float rcp_(float x) {
    float r; asm("v_rcp_f32 %0, %1" : "=v"(r) : "v"(x)); return r;
}

// ---------------- prep: pack W fragment-major bf16; biases pre-scaled by log2e ----------------
// Wpk u16 index = G*16384 + gate*4096 + ks*512 + l4*128 + l15*8 + e
//   holds W[row = gate*128 + G*16 + l15][k = ks*32 + l4*8 + e]  (W = [W_ih | W_hh])
__global__ __launch_bounds__(256) void prep_kernel(
    const float* __restrict__ W_ih, const float* __restrict__ W_hh,
    const float* __restrict__ b_ih, const float* __restrict__ b_hh,
    unsigned short* __restrict__ Wpk, float* __restrict__ biasc)
{
    int gid = blockIdx.x * 256 + threadIdx.x;   // 131072 bf16 elements
    int e = gid & 7;
    int chunk = gid >> 3;                        // 16B chunk id
    int l15 = chunk & 15;
    int l4 = (chunk >> 4) & 3;
    int rest = chunk >> 6;
    int ks = rest & 7;
    int gate = (rest >> 3) & 3;
    int G = rest >> 5;
    int row = gate * 128 + G * 16 + l15;
    int k = ks * 32 + l4 * 8 + e;
    float v = (k < 128) ? W_ih[row * 128 + k] : W_hh[row * 128 + (k - 128)];
    Wpk[gid] = f2bf(v);
    if (gid < 512) {
        float b = b_ih[gid] + b_hh[gid];
        float scale = ((gid >> 7) == 2) ? (2.0f * LOG2E) : (-LOG2E);
        biasc[gid] = b * scale;
    }
}

// ---------------- LSTM + fused partial proj ----------------
// Round-0 skeleton (empirical best across 7 structural variants: short blocks,
// 4 independent blocks/CU, 16 waves/CU; regs exactly 64 VGPR + 64 AGPR = 128/wave).
// Polish, all live-range-neutral:
//  (a) ks=0 B-quads loaded BEFORE __syncthreads (compiler can't hoist across the
//      barrier) — L2 latency overlaps the straggler wait; K-loop starts hot.
//  (b) s_setprio(1) across the K-loop (T5): 4 independent blocks/CU at different
//      phases -> scheduler favors MFMA-phase waves over staging-phase waves.
__global__ __launch_bounds__(256, 4) void lstm_kernel(
    const float* __restrict__ inputs, const float* __restrict__ hx,
    const float* __restrict__ cx, const unsigned short* __restrict__ Wpk,
    const float* __restrict__ biasc, const float* __restrict__ W_out,
    float* __restrict__ projP)
{
    __shared__ __align__(16) unsigned short Abf[64 * 256];  // 32 KB; reused as Hf f32[64][64]
    __shared__ float Wlds[768];
    const int tid = threadIdx.x;

    // bijective chunked XCD swizzle: halves (2t,2t+1) land on the same XCD
    const int orig = blockIdx.x;
    const int xcd = orig & 7, idx = orig >> 3;
    const int wgid = (xcd < XR ? xcd * (XQ + 1) : XR * (XQ + 1) + (xcd - XR) * XQ) + idx;
    const int tile = wgid >> 1, ch = wgid & 1;
    const int brow = tile * 64;

    const int lane = tid & 63;
    const int w = tid >> 6;                          // wave 0..3
    const int l15 = lane & 15, l4 = lane >> 4;
    const int hl = w * 16 + l15;                     // hcol-local 0..63
    const int hcol = ch * 64 + hl;                   // global 0..127

    // ---- stage A = [inputs | hx] as bf16, XOR-swizzled: 4 passes x 16 rows ----
    {
        const int r0 = tid >> 4, seg = tid & 15;     // 16 rows/pass, 16 segs of 16 k
        #pragma unroll
        for (int p = 0; p < 4; ++p) {
            int r = p * 16 + r0;
            int team = brow + r; if (team >= NUM_TEAMS) team = NUM_TEAMS - 1;
            const float* src = (seg < 8) ? inputs + (size_t)team * 128 + seg * 16
                                         : hx + (size_t)team * 128 + (seg - 8) * 16;
            float4 v0 = *reinterpret_cast<const float4*>(src);
            float4 v1 = *reinterpret_cast<const float4*>(src + 4);
            float4 v2 = *reinterpret_cast<const float4*>(src + 8);
            float4 v3 = *reinterpret_cast<const float4*>(src + 12);
            char* lbw = reinterpret_cast<char*>(Abf);
            int base = r * 512 + seg * 32;
            int swz = (r & 7) << 4;
            uint4 q0, q1;
            q0.x = cvtpk(v0.x, v0.y); q0.y = cvtpk(v0.z, v0.w);
            q0.z = cvtpk(v1.x, v1.y); q0.w = cvtpk(v1.z, v1.w);
            q1.x = cvtpk(v2.x, v2.y); q1.y = cvtpk(v2.z, v2.w);
            q1.z = cvtpk(v3.x, v3.y); q1.w = cvtpk(v3.z, v3.w);
            *reinterpret_cast<uint4*>(lbw + (base ^ swz)) = q0;
            *reinterpret_cast<uint4*>(lbw + ((base + 16) ^ swz)) = q1;
        }
        Wlds[tid] = W_out[tid];
        Wlds[256 + tid] = W_out[256 + tid];
        Wlds[512 + tid] = W_out[512 + tid];
    }

    // B fragment base: group G = ch*4 + w, contiguous 1KB per wave-load
    const unsigned short* bpg = Wpk + (size_t)(ch * 4 + w) * 16384 + lane * 8;
    const float bic = biasc[hcol];                   // -c*bi
    const float bfc = biasc[128 + hcol];             // -c*bf
    const float bgc = biasc[256 + hcol];             // +2c*bg
    const float boc = biasc[384 + hcol];             // -c*bo
    const int swzA = (l15 & 7) << 4;
    const int kf = l4 * 16;
    const char* pArow = reinterpret_cast<const char*>(Abf) + l15 * 512;

    f32x4 acc[4][4] = {};                            // [m][gate], 64 AGPRs

    // (a) prefetch ks=0 B-quads pre-barrier: latency hides under straggler wait.
    // Staging regs are dead here -> peak live set unchanged.
    bf16x8 b0 = *(const bf16x8*)(bpg);
    bf16x8 b1 = *(const bf16x8*)(bpg + 4096);
    bf16x8 b2 = *(const bf16x8*)(bpg + 8192);
    bf16x8 b3 = *(const bf16x8*)(bpg + 12288);

    __syncthreads();

    __builtin_amdgcn_s_setprio(1);                   // (b) favor K-loop waves
    // ks = 0 (B prefetched above)
    {
        const int ko = kf ^ swzA;
        #pragma unroll
        for (int m = 0; m < 4; ++m) {
            bf16x8 af = *(const bf16x8*)(pArow + m * 8192 + ko);
            acc[m][0] = __builtin_amdgcn_mfma_f32_16x16x32_bf16(af, b0, acc[m][0], 0, 0, 0);
            acc[m][1] = __builtin_amdgcn_mfma_f32_16x16x32_bf16(af, b1, acc[m][1], 0, 0, 0);
            acc[m][2] = __builtin_amdgcn_mfma_f32_16x16x32_bf16(af, b2, acc[m][2], 0, 0, 0);
            acc[m][3] = __builtin_amdgcn_mfma_f32_16x16x32_bf16(af, b3, acc[m][3], 0, 0, 0);
        }
    }
    #pragma unroll
    for (int ks = 1; ks < 8; ++ks) {                 // K = 256 in steps of 32
        b0 = *(const bf16x8*)(bpg + ks * 512);
        b1 = *(const bf16x8*)(bpg + 4096 + ks * 512);
        b2 = *(const bf16x8*)(bpg + 8192 + ks * 512);
        b3 = *(const bf16x8*)(bpg + 12288 + ks * 512);
        const int ko = (ks * 64 + kf) ^ swzA;
        #pragma unroll
        for (int m = 0; m < 4; ++m) {
            bf16x8 af = *(const bf16x8*)(pArow + m * 8192 + ko);
            acc[m][0] = __builtin_amdgcn_mfma_f32_16x16x32_bf16(af, b0, acc[m][0], 0, 0, 0);
            acc[m][1] = __builtin_amdgcn_mfma_f32_16x16x32_bf16(af, b1, acc[m][1], 0, 0, 0);
            acc[m][2] = __builtin_amdgcn_mfma_f32_16x16x32_bf16(af, b2, acc[m][2], 0, 0, 0);
            acc[m][3] = __builtin_amdgcn_mfma_f32_16x16x32_bf16(af, b3, acc[m][3], 0, 0, 0);
        }
    }
    __builtin_amdgcn_s_setprio(0);

    // issue cx loads before the barrier (latency hides under barrier wait)
    float cxa[16];
    #pragma unroll
    for (int m = 0; m < 4; ++m)
        #pragma unroll
        for (int j = 0; j < 4; ++j) {
            int team = brow + m * 16 + l4 * 4 + j;
            if (team >= NUM_TEAMS) team = NUM_TEAMS - 1;
            cxa[m * 4 + j] = cx[(size_t)team * 128 + hcol];
        }

    __syncthreads();                                 // all A reads done; LDS becomes Hf

    // ---- activations streamed per-m; h -> swizzled f32 [64][64] over Abf ----
    // C/D layout: col = l15 -> hcol, row = l4*4 + j -> team-local
    {
        char* lb = reinterpret_cast<char*>(Abf);
        #pragma unroll
        for (int m = 0; m < 4; ++m) {
            #pragma unroll
            for (int j = 0; j < 4; ++j) {
                float si = rcp_(1.0f + exp2_(fmaf(acc[m][0][j], -LOG2E, bic)));
                float sf = rcp_(1.0f + exp2_(fmaf(acc[m][1][j], -LOG2E, bfc)));
                float tg = fmaf(-2.0f, rcp_(1.0f + exp2_(fmaf(acc[m][2][j], 2.0f * LOG2E, bgc))), 1.0f);
                float so = rcp_(1.0f + exp2_(fmaf(acc[m][3][j], -LOG2E, boc)));
                float cn = fmaf(sf, cxa[m * 4 + j], si * tg);
                float tc = fmaf(-2.0f, rcp_(1.0f + exp2_(cn * (2.0f * LOG2E))), 1.0f);
                float hn = so * tc;
                int t = m * 16 + l4 * 4 + j;
                *reinterpret_cast<float*>(lb + ((t * 256 + hl * 4) ^ ((t & 7) << 4))) = hn;
            }
        }
    }
    __syncthreads();

    // ---- fused partial proj: 4 threads/team, 16 hcols each, 6 partial outputs ----
    {
        int tl = tid >> 2, sub = tid & 3;            // team-local 0..63, sub 0..3
        const char* lb = reinterpret_cast<const char*>(Abf);
        int hbase = tl * 256 + sub * 64;
        int hswz = (tl & 7) << 4;
        float a0 = 0.f, a1 = 0.f, a2 = 0.f, a3 = 0.f, a4 = 0.f, a5 = 0.f;
        #pragma unroll
        for (int c = 0; c < 4; ++c) {
            f32x4 h4 = *reinterpret_cast<const f32x4*>(lb + ((hbase + c * 16) ^ hswz));
            #pragma unroll
            for (int i = 0; i < 4; ++i) {
                float h = h4[i];
                int col = ch * 64 + sub * 16 + c * 4 + i;    // global hcol 0..127
                a0 += h * Wlds[col];       a1 += h * Wlds[256 + col]; a2 += h * Wlds[512 + col];
                a3 += h * Wlds[128 + col]; a4 += h * Wlds[384 + col]; a5 += h * Wlds[640 + col];
            }
        }
        a0 += __shfl_xor(a0, 1); a1 += __shfl_xor(a1, 1); a2 += __shfl_xor(a2, 1);
        a3 += __shfl_xor(a3, 1); a4 += __shfl_xor(a4, 1); a5 += __shfl_xor(a5, 1);
        a0 += __shfl_xor(a0, 2); a1 += __shfl_xor(a1, 2); a2 += __shfl_xor(a2, 2);
        a3 += __shfl_xor(a3, 2); a4 += __shfl_xor(a4, 2); a5 += __shfl_xor(a5, 2);
        int team = brow + tl;
        if (sub == 0 && team < NUM_TEAMS) {
            float4* o = reinterpret_cast<float4*>(projP + (size_t)team * 16 + ch * 8);
            o[0] = make_float4(a0, a1, a2, a2);      // home partial
            o[1] = make_float4(a3, a4, a5, a5);      // away partial
        }
    }
}

// ---------------- match head: sum half-partials; logits + b_out ; softmax ----------------
// Output coalescing: 12 B/thread routed through 3 KB LDS -> 192 contiguous
// float4 stores per block (vs 3 strided dword stores/thread).
__global__ __launch_bounds__(256) void match_kernel(
    const int* __restrict__ matches, const float* __restrict__ projP,
    const float* __restrict__ b_out, float* __restrict__ out)
{
    __shared__ __align__(16) float ol[768];
    const int t = threadIdx.x;
    int m = blockIdx.x * 256 + t;
    int mm = (m < NUM_MATCHES) ? m : NUM_MATCHES - 1;
    int2 mi = reinterpret_cast<const int2*>(matches)[mm];
    const float4* pp = reinterpret_cast<const float4*>(projP);
    float4 h0 = pp[(size_t)mi.x * 4 + 0];            // half0 home
    float4 h1 = pp[(size_t)mi.x * 4 + 2];            // half1 home
    float4 a0 = pp[(size_t)mi.y * 4 + 1];            // half0 away
    float4 a1 = pp[(size_t)mi.y * 4 + 3];            // half1 away
    float l0 = h0.x + h1.x + a0.x + a1.x + b_out[0];
    float l1 = h0.y + h1.y + a0.y + a1.y + b_out[1];
    float l2 = h0.z + h1.z + a0.z + a1.z + b_out[2];
    float mx = fmaxf(l0, fmaxf(l1, l2));
    float e0 = __expf(l0 - mx), e1 = __expf(l1 - mx), e2 = __expf(l2 - mx);
    float inv = 1.0f / (e0 + e1 + e2);
    ol[t * 3 + 0] = e0 * inv;                        // stride-3 words: gcd(3,32)=1, conflict-free
    ol[t * 3 + 1] = e1 * inv;
    ol[t * 3 + 2] = e2 * inv;
    __syncthreads();
    if (t < 192) {
        size_t fi = (size_t)blockIdx.x * 192 + t;    // float4 index; 3*NUM_MATCHES/4 = 750000
        if (fi < 750000)
            reinterpret_cast<float4*>(out)[fi] = reinterpret_cast<const float4*>(ol)[t];
    }
}

extern "C" void kernel_launch(void* const* d_in, const int* in_sizes, int n_in,
                              void* d_out, int out_size, void* d_ws, size_t ws_size,
                              hipStream_t stream) {
    const float* inputs = (const float*)d_in[0];
    const float* hx     = (const float*)d_in[1];
    const float* cx     = (const float*)d_in[2];
    const int*   matches= (const int*)d_in[3];
    const float* W_ih   = (const float*)d_in[4];
    const float* W_hh   = (const float*)d_in[5];
    const float* b_ih   = (const float*)d_in[6];
    const float* b_hh   = (const float*)d_in[7];
    const float* W_out  = (const float*)d_in[8];
    const float* b_out  = (const float*)d_in[9];
    float* out = (float*)d_out;

    char* ws = (char*)d_ws;
    unsigned short* Wpk  = (unsigned short*)ws;                  // 256 KB fragment-major
    float* biasc         = (float*)(ws + 262144);                // 2 KB
    float* projP         = (float*)(ws + (1 << 20));             // 100000*16*4 = 6.4 MB

    prep_kernel <<<512, 256, 0, stream>>>(W_ih, W_hh, b_ih, b_hh, Wpk, biasc);
    lstm_kernel <<<NWG, 256, 0, stream>>>(inputs, hx, cx, Wpk, biasc, W_out, projP);
    match_kernel<<<(NUM_MATCHES + 255) / 256, 256, 0, stream>>>(matches, projP, b_out, out);
}